// Round 7
// baseline (358.525 us; speedup 1.0000x reference)
//
#include <hip/hip_runtime.h>

typedef unsigned short u16;
typedef short s16x8 __attribute__((ext_vector_type(8)));
typedef u16 u16x4 __attribute__((ext_vector_type(4)));
typedef float f32x4 __attribute__((ext_vector_type(4)));

#define B_ 32
#define L_ 256
#define D_ 1024
#define H_ 8
#define DQ_ 128
#define DS_ 64
#define DM_ 256
#define DF_ 4096

__device__ __forceinline__ u16 f2bf(float f) {
  unsigned u = __float_as_uint(f);
  unsigned r = (u + 0x7FFFu + ((u >> 16) & 1u)) >> 16;
  return (u16)r;
}
__device__ __forceinline__ float bf2f(u16 x) {
  return __uint_as_float(((unsigned)x) << 16);
}

__device__ __forceinline__ f32x4 mfma16(s16x8 a, s16x8 b, f32x4 c) {
  return __builtin_amdgcn_mfma_f32_16x16x32_bf16(a, b, c, 0, 0, 0);
}

#define GLDS16(g, l)                                                        \
  __builtin_amdgcn_global_load_lds(                                         \
      (__attribute__((address_space(1))) const void*)(g),                   \
      (__attribute__((address_space(3))) void*)(l), 16, 0, 0)

// ---------------- 32x32 transpose+convert tile helper
__device__ __forceinline__ void tile_tr(const float* __restrict__ ip,
                                        u16* __restrict__ op, int K, int N,
                                        int bx, int by, float (*t)[33], int tid) {
  const int tx = tid & 31, ty = tid >> 5;
  const long n0 = (long)bx * 32, k0 = (long)by * 32;
#pragma unroll
  for (int i = 0; i < 4; ++i)
    t[ty + i * 8][tx] = ip[(k0 + ty + i * 8) * (long)N + n0 + tx];
  __syncthreads();
#pragma unroll
  for (int i = 0; i < 4; ++i)
    op[(n0 + ty + i * 8) * (long)K + k0 + tx] = f2bf(t[tx][ty + i * 8]);
}

// ---------------- mega K1: everything that depends only on raw inputs.
// grid: [0,512) gemv (self-computes hid) | [512,560) qkv-direct proj |
//       [560,1584) owT | [1584,5680) w1T | [5680,9776) w2T
__global__ __launch_bounds__(256) void mega1(
    const float* __restrict__ sf, const float* __restrict__ b1w,
    const float* __restrict__ b1b, const float* __restrict__ b2w,
    const float* __restrict__ b2b, float* __restrict__ biasb,
    const float* __restrict__ src, const float* __restrict__ qw,
    const float* __restrict__ kw, const float* __restrict__ vw,
    const float* __restrict__ qb, const float* __restrict__ kb,
    const float* __restrict__ vb, u16* __restrict__ q0, u16* __restrict__ k0,
    u16* __restrict__ v0T, const float* __restrict__ ow,
    const float* __restrict__ w1, const float* __restrict__ w2,
    u16* __restrict__ owT, u16* __restrict__ w1T, u16* __restrict__ w2T) {
  const int b = blockIdx.x;
  const int tid = threadIdx.x;
  __shared__ float s_sf[DS_];
  __shared__ int wcnt[4];
  __shared__ float sv[DM_];
  __shared__ int si[DM_];
  __shared__ int snnz;
  __shared__ u16 smA[128 * 32];
  __shared__ u16 smB[128 * 40];  // pad 40: kills transpose-write conflicts
  __shared__ float t[32][33];
  if (b < 512) {
    // ---- bias GEMV, hid computed locally (no dependency on any prior kernel)
    const int h = b >> 6;
    const int n0 = (b & 63) << 10;
    if (tid < DS_) s_sf[tid] = sf[tid];
    __syncthreads();
    float a = b1b[h * DM_ + tid];
    const float* wp = b1w + (long)h * DS_ * DM_ + tid;
#pragma unroll 8
    for (int s = 0; s < DS_; ++s) a += s_sf[s] * wp[s * DM_];
    a = fmaxf(a, 0.f);
    const unsigned long long bal = __ballot(a > 0.f);
    const int lane = tid & 63, wv = tid >> 6;
    const int pc = __popcll(bal);
    if (lane == 0) wcnt[wv] = pc;
    __syncthreads();
    int base = 0;
    for (int i = 0; i < wv; ++i) base += wcnt[i];
    const int pos = base + __popcll(bal & ((1ull << lane) - 1ull));
    if (a > 0.f) { sv[pos] = a; si[pos] = tid; }
    if (tid == 255) snnz = base + pc;
    __syncthreads();
    const int nnz = snnz;
    const float* wb = b2w + (long)h * DM_ * 65536 + n0 + tid * 4;
    float4 acc = {0.f, 0.f, 0.f, 0.f};
    int j = 0;
    for (; j + 4 <= nnz; j += 4) {
      const float4 a0 = *(const float4*)(wb + (long)si[j] * 65536);
      const float4 a1 = *(const float4*)(wb + (long)si[j + 1] * 65536);
      const float4 a2 = *(const float4*)(wb + (long)si[j + 2] * 65536);
      const float4 a3 = *(const float4*)(wb + (long)si[j + 3] * 65536);
      const float v0 = sv[j], v1 = sv[j + 1], v2 = sv[j + 2], v3 = sv[j + 3];
      acc.x += v0 * a0.x + v1 * a1.x + v2 * a2.x + v3 * a3.x;
      acc.y += v0 * a0.y + v1 * a1.y + v2 * a2.y + v3 * a3.y;
      acc.z += v0 * a0.z + v1 * a1.z + v2 * a2.z + v3 * a3.z;
      acc.w += v0 * a0.w + v1 * a1.w + v2 * a2.w + v3 * a3.w;
    }
    for (; j < nnz; ++j) {
      const float4 a0 = *(const float4*)(wb + (long)si[j] * 65536);
      const float v0 = sv[j];
      acc.x += v0 * a0.x; acc.y += v0 * a0.y; acc.z += v0 * a0.z; acc.w += v0 * a0.w;
    }
    const float4 bb = *(const float4*)(b2b + (long)h * 65536 + n0 + tid * 4);
    float4 o = {acc.x + bb.x, acc.y + bb.y, acc.z + bb.z, acc.w + bb.w};
    *(float4*)(biasb + (long)h * 65536 + n0 + tid * 4) = o;
  } else if (b < 560) {
    // ---- QKV projection direct from raw src (f32) and qw/kw/vw (f32 [D][DQ])
    const int r = b - 512;
    const int z = r >> 1, sel = z >> 3, h = z & 7;
    const long tm = (long)(r & 1) * 128;
    const float* wsrc = (sel == 0 ? qw : (sel == 1 ? kw : vw)) + (long)h * D_ * DQ_;
    const float* bias = (sel == 0 ? qb : (sel == 1 ? kb : vb)) + h * DQ_;
    const int lane = tid & 63;
    const int wv = tid >> 6;
    const int wr = wv >> 1, wc = wv & 1;
    f32x4 acc[4][4];
#pragma unroll
    for (int m = 0; m < 4; ++m)
#pragma unroll
      for (int n = 0; n < 4; ++n) acc[m][n] = (f32x4){0.f, 0.f, 0.f, 0.f};
    for (int k0_ = 0; k0_ < D_; k0_ += 32) {
      // A: src rows [tm,tm+128) cols [k0_,k0_+32) f32 -> bf16 smA[row][32]
#pragma unroll
      for (int jj = 0; jj < 4; ++jj) {
        const int f4 = jj * 256 + tid;
        const int row = f4 >> 3, c4 = f4 & 7;
        const float4 v = *(const float4*)(src + (tm + row) * (long)D_ + k0_ + c4 * 4);
        u16x4 o = {f2bf(v.x), f2bf(v.y), f2bf(v.z), f2bf(v.w)};
        *(u16x4*)(&smA[row * 32 + c4 * 4]) = o;
      }
      // B: qw rows [k0_,k0_+32) x 128 cols, transposed -> smB[n][40] (bf16)
#pragma unroll
      for (int jj = 0; jj < 4; ++jj) {
        const int f4 = jj * 256 + tid;
        const int krow = f4 >> 5, n4 = f4 & 31;
        const float4 v = *(const float4*)(wsrc + (k0_ + krow) * (long)DQ_ + n4 * 4);
        smB[(n4 * 4 + 0) * 40 + krow] = f2bf(v.x);
        smB[(n4 * 4 + 1) * 40 + krow] = f2bf(v.y);
        smB[(n4 * 4 + 2) * 40 + krow] = f2bf(v.z);
        smB[(n4 * 4 + 3) * 40 + krow] = f2bf(v.w);
      }
      __syncthreads();
      s16x8 af[4], bf[4];
      const int ka = (lane >> 4) * 8;
      const int ra = wr * 64 + (lane & 15);
      const int rb = wc * 64 + (lane & 15);
#pragma unroll
      for (int m = 0; m < 4; ++m) af[m] = *(const s16x8*)&smA[(ra + m * 16) * 32 + ka];
#pragma unroll
      for (int n = 0; n < 4; ++n) bf[n] = *(const s16x8*)&smB[(rb + n * 16) * 40 + ka];
#pragma unroll
      for (int m = 0; m < 4; ++m)
#pragma unroll
        for (int n = 0; n < 4; ++n) acc[m][n] = mfma16(af[m], bf[n], acc[m][n]);
      __syncthreads();
    }
    const long crow0 = tm + wr * 64 + ((lane >> 4) * 4);
    const long ccol0 = wc * 64 + (lane & 15);
#pragma unroll
    for (int m = 0; m < 4; ++m)
#pragma unroll
      for (int n = 0; n < 4; ++n)
#pragma unroll
        for (int i = 0; i < 4; ++i) {
          const long row = crow0 + m * 16 + i;
          const long col = ccol0 + n * 16;
          const float v = acc[m][n][i] + bias[col];
          if (sel < 2) {
            u16* o = (sel == 0 ? q0 : k0) + (long)h * L_ * DQ_;
            o[row * DQ_ + col] = f2bf(v);
          } else {
            v0T[(long)h * DQ_ * L_ + col * L_ + row] = f2bf(v);
          }
        }
  } else if (b < 1584) {
    const int rem = b - 560;
    tile_tr(ow, owT, D_, D_, rem & 31, rem >> 5, t, tid);
  } else if (b < 5680) {
    const int rem = b - 1584;
    tile_tr(w1, w1T, D_, DF_, rem & 127, rem >> 7, t, tid);
  } else {
    const int rem = b - 5680;
    tile_tr(w2, w2T, DF_, D_, rem & 31, rem >> 5, t, tid);
  }
}

// ---------------- attention (b=0): one wave per (head, 16-row tile), bias fused
__global__ __launch_bounds__(64) void attn_kernel(
    const u16* __restrict__ q0, const u16* __restrict__ k0,
    const u16* __restrict__ v0T, const float* __restrict__ biasb,
    const int* __restrict__ mask, u16* __restrict__ hidden) {
  __shared__ char pbuf[8192];  // [16 rows][256 cols] bf16, XOR-swizzled
  const int lane = threadIdx.x;
  const int h = blockIdx.y;
  const int r0 = blockIdx.x * 16;
  const int lg = lane >> 4;
  const int ll = lane & 15;
  const u16* q = q0 + (long)h * L_ * DQ_;
  const u16* k = k0 + (long)h * L_ * DQ_;
  const u16* v = v0T + (long)h * DQ_ * L_;

  s16x8 aq[4];
#pragma unroll
  for (int kk = 0; kk < 4; ++kk)
    aq[kk] = *(const s16x8*)(q + (long)(r0 + ll) * DQ_ + kk * 32 + lg * 8);
  float sc[16][4];
  const float scale = 0.08838834764831845f;  // 1/sqrt(128)
#pragma unroll
  for (int t = 0; t < 16; ++t) {
    f32x4 a = {0.f, 0.f, 0.f, 0.f};
#pragma unroll
    for (int kk = 0; kk < 4; ++kk) {
      s16x8 bf = *(const s16x8*)(k + (long)(t * 16 + ll) * DQ_ + kk * 32 + lg * 8);
      a = mfma16(aq[kk], bf, a);
    }
#pragma unroll
    for (int i = 0; i < 4; ++i) {
      const int row = r0 + lg * 4 + i;
      const int col = t * 16 + ll;
      float s = a[i] * scale;
      if (mask[row * L_ + col] != 0) s = 1e-9f;
      sc[t][i] = s;
    }
  }
#pragma unroll
  for (int i = 0; i < 4; ++i) {
    float mx = sc[0][i];
#pragma unroll
    for (int t = 1; t < 16; ++t) mx = fmaxf(mx, sc[t][i]);
#pragma unroll
    for (int d = 1; d < 16; d <<= 1) mx = fmaxf(mx, __shfl_xor(mx, d));
    float sum = 0.f;
#pragma unroll
    for (int t = 0; t < 16; ++t) {
      const float e = __expf(sc[t][i] - mx);
      sc[t][i] = e;
      sum += e;
    }
#pragma unroll
    for (int d = 1; d < 16; d <<= 1) sum += __shfl_xor(sum, d);
    const float inv = 1.f / sum;
    const int row = r0 + lg * 4 + i;
#pragma unroll
    for (int t = 0; t < 16; ++t)
      sc[t][i] = sc[t][i] * inv + biasb[(long)h * 65536 + (long)row * 256 + t * 16 + ll];
  }
  // write P (bf16) swizzled; PV (within-wave LDS dep -> compiler waits lgkmcnt)
#pragma unroll
  for (int t = 0; t < 16; ++t)
#pragma unroll
    for (int i = 0; i < 4; ++i) {
      const int lr = lg * 4 + i;
      const int cb = (t * 16 + ll) * 2;
      *(u16*)(pbuf + lr * 512 + (cb ^ ((lr & 7) << 4))) = f2bf(sc[t][i]);
    }
  s16x8 paf[8];
#pragma unroll
  for (int kk = 0; kk < 8; ++kk)
    paf[kk] = *(const s16x8*)(pbuf + ll * 512 + ((kk * 64 + lg * 16) ^ ((ll & 7) << 4)));
#pragma unroll
  for (int n = 0; n < 8; ++n) {
    f32x4 a = {0.f, 0.f, 0.f, 0.f};
#pragma unroll
    for (int kk = 0; kk < 8; ++kk) {
      s16x8 bf = *(const s16x8*)(v + (long)(n * 16 + ll) * 256 + kk * 32 + lg * 8);
      a = mfma16(paf[kk], bf, a);
    }
#pragma unroll
    for (int i = 0; i < 4; ++i) {
      const int row = r0 + lg * 4 + i;
      const int col = n * 16 + ll;
      hidden[(long)row * 1024 + h * 128 + col] = f2bf(a[i]);
    }
  }
}

// ---------------- shared 128x128xK m97 GEMM core (A,BT pre-offset to tile)
__device__ __forceinline__ void g128_core(const u16* __restrict__ A,
                                          const u16* __restrict__ BT, int K,
                                          u16* smA, u16* smB,
                                          f32x4 (&acc)[4][4]) {
  const int tid = threadIdx.x;
  const int lane = tid & 63;
  const int wv = tid >> 6;
  const int wr = wv >> 1, wc = wv & 1;
  const u16* ga = A + (long)(tid >> 2) * K + (tid & 3) * 8;
  const u16* gb = BT + (long)(tid >> 2) * K + (tid & 3) * 8;
  const long rstep = 64L * K;
  u16* la = &smA[tid * 8];
  u16* lb = &smB[tid * 8];
#pragma unroll
  for (int m = 0; m < 4; ++m)
#pragma unroll
    for (int n = 0; n < 4; ++n) acc[m][n] = (f32x4){0.f, 0.f, 0.f, 0.f};
  for (int k0 = 0; k0 < K; k0 += 32) {
    GLDS16(ga + k0, la);
    GLDS16(ga + rstep + k0, la + 64 * 32);
    GLDS16(gb + k0, lb);
    GLDS16(gb + rstep + k0, lb + 64 * 32);
    __syncthreads();
    s16x8 af[4], bf[4];
    const int ka = (lane >> 4) * 8;
    const int ra = wr * 64 + (lane & 15);
    const int rb = wc * 64 + (lane & 15);
#pragma unroll
    for (int m = 0; m < 4; ++m) af[m] = *(const s16x8*)&smA[(ra + m * 16) * 32 + ka];
#pragma unroll
    for (int n = 0; n < 4; ++n) bf[n] = *(const s16x8*)&smB[(rb + n * 16) * 32 + ka];
#pragma unroll
    for (int m = 0; m < 4; ++m)
#pragma unroll
      for (int n = 0; n < 4; ++n) acc[m][n] = mfma16(af[m], bf[n], acc[m][n]);
    __syncthreads();
  }
}

// ---------------- m97-style 128x128 GEMM, f32 out +bias (attn out proj)
__global__ __launch_bounds__(256) void gemm_bt(
    const u16* __restrict__ A, const u16* __restrict__ BT, float* __restrict__ C,
    const float* __restrict__ bias, int K, int ldc) {
  __shared__ u16 smA[128 * 32];
  __shared__ u16 smB[128 * 32];
  const int tid = threadIdx.x;
  const long tm = (long)blockIdx.x * 128;
  const long tn = (long)blockIdx.y * 128;
  f32x4 acc[4][4];
  g128_core(A + tm * K, BT + tn * K, K, smA, smB, acc);
  const int lane = tid & 63;
  const int wv = tid >> 6;
  const int wr = wv >> 1, wc = wv & 1;
  const long crow0 = tm + wr * 64 + ((lane >> 4) * 4);
  const long ccol0 = tn + wc * 64 + (lane & 15);
#pragma unroll
  for (int m = 0; m < 4; ++m)
#pragma unroll
    for (int n = 0; n < 4; ++n)
#pragma unroll
      for (int i = 0; i < 4; ++i) {
        const long row = crow0 + m * 16 + i;
        const long col = ccol0 + n * 16;
        C[row * (long)ldc + col] = acc[m][n][i] + bias[col];
      }
}

// ---------------- 8-phase 256xBN deep-pipelined GEMM (T1+T2+T4+T5)
// EPI: 1 = bf16 out relu(+bias); 2 = bf16 out +bias +bf16 residual
template <int BN, int EPI>
__global__ __launch_bounds__(512, 2) void gemm8p(
    const u16* __restrict__ A, const u16* __restrict__ BT, void* __restrict__ Cv,
    const float* __restrict__ bias, const void* __restrict__ R, int M, int N,
    int K, int ldc) {
  extern __shared__ char lds[];
  constexpr int NR = BN / 64;
  constexpr int NHB = BN / 128;
  constexpr int BUF = 32768 + BN * 128;
  constexpr int WST = (NHB == 2) ? 4 : 2;
  const int tid = threadIdx.x;
  const int lane = tid & 63;
  const int w = tid >> 6;
  const int wr = w >> 2, wc = w & 3;

  const int total = gridDim.x;
  int bid = blockIdx.x;
  int s = ((total & 7) == 0) ? ((bid & 7) * (total >> 3) + (bid >> 3)) : bid;
  const int gn = N / BN;
  const long tm = (long)(s / gn) * 256;
  const long tn = (long)(s % gn) * BN;
  const int NT = K >> 6;

  auto stageA = [&](int half, int t) {
    char* hb = lds + (long)(t & 1) * BUF + half * 16384;
    const u16* g = A + (tm + half * 128) * (long)K + (long)t * 64;
#pragma unroll
    for (int j = 0; j < 2; ++j) {
      const int idx = j * 512 + tid;
      const int r = idx >> 3;
      const int c16 = (idx & 7) ^ (r & 7);
      GLDS16(g + (long)r * K + c16 * 8, hb + idx * 16);
    }
  };
  auto stageB = [&](int half, int t) {
    char* hb = lds + (long)(t & 1) * BUF + 32768 + half * 16384;
    const u16* g = BT + (tn + half * 128) * (long)K + (long)t * 64;
#pragma unroll
    for (int j = 0; j < 2; ++j) {
      const int idx = j * 512 + tid;
      const int r = idx >> 3;
      const int c16 = (idx & 7) ^ (r & 7);
      GLDS16(g + (long)r * K + c16 * 8, hb + idx * 16);
    }
  };

  stageA(0, 0);
  stageA(1, 0);
  stageB(0, 0);
  if (NHB == 2) stageB(1, 0);
  stageB(0, 1);
  if (NHB == 2) stageB(1, 1);
  asm volatile("s_waitcnt vmcnt(%0)" ::"n"(WST) : "memory");
  __builtin_amdgcn_s_barrier();

  f32x4 acc[8][NR];
#pragma unroll
  for (int m = 0; m < 8; ++m)
#pragma unroll
    for (int n = 0; n < NR; ++n) acc[m][n] = (f32x4){0.f, 0.f, 0.f, 0.f};

  const int lk = (lane >> 4) * 16;
  const int lr = lane & 15;

  for (int t = 0; t < NT; ++t) {
    const char* bp = lds + (long)(t & 1) * BUF;
    s16x8 bfr[NR][2];
#pragma unroll
    for (int p = 0; p < 4; ++p) {
      if (p == 0) {
#pragma unroll
        for (int ni = 0; ni < NR; ++ni) {
          const int brow = wc * (BN / 4) + ni * 16 + lr;
#pragma unroll
          for (int ks = 0; ks < 2; ++ks) {
            const int kb = (ks * 64 + lk) ^ ((brow & 7) << 4);
            bfr[ni][ks] = *(const s16x8*)(bp + 32768 + brow * 128 + kb);
          }
        }
      }
      s16x8 afr[2][2];
#pragma unroll
      for (int rI = 0; rI < 2; ++rI) {
        const int arow = wr * 128 + (2 * p + rI) * 16 + lr;
#pragma unroll
        for (int ks = 0; ks < 2; ++ks) {
          const int kb = (ks * 64 + lk) ^ ((arow & 7) << 4);
          afr[rI][ks] = *(const s16x8*)(bp + arow * 128 + kb);
        }
      }
      if (p == 0) { if (t + 1 < NT) stageA(0, t + 1); }
      else if (p == 1) { if (t + 1 < NT) stageA(1, t + 1); }
      else if (p == 2) { if (t + 2 < NT) stageB(0, t + 2); }
      else { if (NHB == 2 && t + 2 < NT) stageB(1, t + 2); }
      __builtin_amdgcn_s_barrier();
      __builtin_amdgcn_s_setprio(1);
#pragma unroll
      for (int rI = 0; rI < 2; ++rI)
#pragma unroll
        for (int ni = 0; ni < NR; ++ni)
#pragma unroll
          for (int ks = 0; ks < 2; ++ks)
            acc[2 * p + rI][ni] = mfma16(afr[rI][ks], bfr[ni][ks], acc[2 * p + rI][ni]);
      __builtin_amdgcn_s_setprio(0);
      if (p == 3) {
        if (t + 2 < NT) {
          asm volatile("s_waitcnt vmcnt(%0)" ::"n"(WST) : "memory");
        } else if (t + 1 < NT) {
          asm volatile("s_waitcnt vmcnt(0)" ::: "memory");
        }
      }
      __builtin_amdgcn_s_barrier();
    }
  }

  const long crow0 = tm + wr * 128 + ((lane >> 4) * 4);
  const long ccol0 = tn + wc * (BN / 4) + lr;
#pragma unroll
  for (int m = 0; m < 8; ++m) {
#pragma unroll
    for (int n = 0; n < NR; ++n) {
#pragma unroll
      for (int i = 0; i < 4; ++i) {
        const long row = crow0 + m * 16 + i;
        const long col = ccol0 + n * 16;
        const float v = acc[m][n][i] + bias[col];
        if constexpr (EPI == 1) {
          ((u16*)Cv)[row * (long)ldc + col] = f2bf(fmaxf(v, 0.f));
        } else {
          const float r = bf2f(((const u16*)R)[row * (long)ldc + col]);
          ((u16*)Cv)[row * (long)ldc + col] = f2bf(v + r);
        }
      }
    }
  }
}

// ---------------- layernorm over D=1024
// MODE 0: in f32 + add f32 (attn row, row%L), out bf16
// MODE 1: in bf16, out f32
template <int MODE>
__global__ __launch_bounds__(256) void ln_kernel(
    const void* __restrict__ in0v, const float* __restrict__ add1,
    const float* __restrict__ g, const float* __restrict__ bb,
    void* __restrict__ outv) {
  const int tid = threadIdx.x;
  const long row = blockIdx.x;
  float4 v;
  if constexpr (MODE == 0) {
    v = ((const float4*)((const float*)in0v + row * D_))[tid];
    const float4 u = ((const float4*)(add1 + (row & (L_ - 1)) * D_))[tid];
    v.x += u.x; v.y += u.y; v.z += u.z; v.w += u.w;
  } else {
    const uint2 pk = *(const uint2*)((const u16*)in0v + row * D_ + tid * 4);
    v.x = __uint_as_float((pk.x & 0xFFFFu) << 16);
    v.y = __uint_as_float(pk.x & 0xFFFF0000u);
    v.z = __uint_as_float((pk.y & 0xFFFFu) << 16);
    v.w = __uint_as_float(pk.y & 0xFFFF0000u);
  }
  float s = v.x + v.y + v.z + v.w;
  float q = v.x * v.x + v.y * v.y + v.z * v.z + v.w * v.w;
#pragma unroll
  for (int d = 1; d < 64; d <<= 1) { s += __shfl_xor(s, d); q += __shfl_xor(q, d); }
  __shared__ float ss[4], sq[4];
  const int wv = tid >> 6;
  if ((tid & 63) == 0) { ss[wv] = s; sq[wv] = q; }
  __syncthreads();
  s = ss[0] + ss[1] + ss[2] + ss[3];
  q = sq[0] + sq[1] + sq[2] + sq[3];
  const float mu = s * (1.f / D_);
  const float var = q * (1.f / D_) - mu * mu;
  const float rs = rsqrtf(var + 1e-5f);
  const float4 gv = ((const float4*)g)[tid];
  const float4 bv = ((const float4*)bb)[tid];
  float4 o;
  o.x = (v.x - mu) * rs * gv.x + bv.x;
  o.y = (v.y - mu) * rs * gv.y + bv.y;
  o.z = (v.z - mu) * rs * gv.z + bv.z;
  o.w = (v.w - mu) * rs * gv.w + bv.w;
  if constexpr (MODE == 0) {
    uint2 pk;
    pk.x = (unsigned)f2bf(o.x) | ((unsigned)f2bf(o.y) << 16);
    pk.y = (unsigned)f2bf(o.z) | ((unsigned)f2bf(o.w) << 16);
    *(uint2*)((u16*)outv + row * D_ + tid * 4) = pk;
  } else {
    ((float4*)((float*)outv + row * D_))[tid] = o;
  }
}

extern "C" void kernel_launch(void* const* d_in, const int* in_sizes, int n_in,
                              void* d_out, int out_size, void* d_ws, size_t ws_size,
                              hipStream_t stream) {
  (void)in_sizes; (void)n_in; (void)out_size; (void)ws_size;
  const float* src = (const float*)d_in[0];
  const float* sf = (const float*)d_in[1];
  const int* mask = (const int*)d_in[2];
  const float* qw = (const float*)d_in[3];
  const float* qb = (const float*)d_in[4];
  const float* kw = (const float*)d_in[5];
  const float* kb = (const float*)d_in[6];
  const float* vw = (const float*)d_in[7];
  const float* vb = (const float*)d_in[8];
  const float* b1w = (const float*)d_in[9];
  const float* b1b = (const float*)d_in[10];
  const float* b2w = (const float*)d_in[11];
  const float* b2b = (const float*)d_in[12];
  const float* ow = (const float*)d_in[13];
  const float* ob = (const float*)d_in[14];
  const float* ln1g = (const float*)d_in[15];
  const float* ln1b = (const float*)d_in[16];
  const float* ln2g = (const float*)d_in[17];
  const float* ln2b = (const float*)d_in[18];
  const float* w1 = (const float*)d_in[19];
  const float* bf1 = (const float*)d_in[20];
  const float* w2 = (const float*)d_in[21];
  const float* bf2 = (const float*)d_in[22];
  float* out = (float*)d_out;

  char* ws = (char*)d_ws;
  size_t off = 0;
  auto alloc = [&](size_t bytes) {
    void* p = ws + off;
    off += (bytes + 255) & ~(size_t)255;
    return p;
  };
  u16* owT = (u16*)alloc((size_t)D_ * D_ * 2);
  u16* w1T = (u16*)alloc((size_t)DF_ * D_ * 2);
  u16* w2T = (u16*)alloc((size_t)D_ * DF_ * 2);
  u16* q0 = (u16*)alloc((size_t)H_ * L_ * DQ_ * 2);
  u16* k0 = (u16*)alloc((size_t)H_ * L_ * DQ_ * 2);
  u16* v0T = (u16*)alloc((size_t)H_ * DQ_ * L_ * 2);
  float* biasb = (float*)alloc((size_t)H_ * L_ * L_ * 4);
  u16* hidden = (u16*)alloc((size_t)L_ * D_ * 2);
  float* attnvec = (float*)alloc((size_t)L_ * D_ * 4);
  u16* xb = (u16*)alloc((size_t)B_ * L_ * D_ * 2);
  u16* ffnh = (u16*)alloc((size_t)B_ * L_ * DF_ * 2);
  u16* yb = (u16*)alloc((size_t)B_ * L_ * D_ * 2);

  hipFuncSetAttribute((const void*)gemm8p<256, 1>,
                      hipFuncAttributeMaxDynamicSharedMemorySize, 131072);
  hipFuncSetAttribute((const void*)gemm8p<128, 2>,
                      hipFuncAttributeMaxDynamicSharedMemorySize, 98304);

  const dim3 b256(256);
  // K1: gemv(self-hid) || qkv-direct || ow/w1/w2 transposes — raw inputs only
  mega1<<<dim3(9776), b256, 0, stream>>>(sf, b1w, b1b, b2w, b2b, biasb, src, qw,
                                         kw, vw, qb, kb, vb, q0, k0, v0T, ow, w1,
                                         w2, owT, w1T, w2T);
  // K2: attention (b=0), bias fused post-softmax -> hidden
  attn_kernel<<<dim3(16, H_), dim3(64), 0, stream>>>(q0, k0, v0T, biasb, mask,
                                                     hidden);
  // K3: attn out projection -> attnvec f32
  gemm_bt<<<dim3(2, 8), b256, 0, stream>>>(hidden, owT, attnvec, ob, D_, D_);
  // K4: LN1 -> xb bf16
  ln_kernel<0><<<dim3(B_ * L_), b256, 0, stream>>>(src, attnvec, ln1g, ln1b, xb);
  // K5: FFN1 relu(x @ w1 + bf1) -> ffnh bf16
  gemm8p<256, 1><<<dim3(512), dim3(512), 131072, stream>>>(
      xb, w1T, ffnh, bf1, nullptr, B_ * L_, DF_, D_, DF_);
  // K6: FFN2 yb = bf16(ffnh @ w2 + bf2 + xb)
  gemm8p<128, 2><<<dim3(256), dim3(512), 98304, stream>>>(
      ffnh, w2T, yb, bf2, xb, B_ * L_, D_, DF_, D_);
  // K7: LN2 -> d_out (f32)
  ln_kernel<1><<<dim3(B_ * L_), b256, 0, stream>>>(yb, nullptr, ln2g, ln2b, out);
}

// Round 8
// 330.323 us; speedup vs baseline: 1.0854x; 1.0854x over previous
//
#include <hip/hip_runtime.h>

typedef unsigned short u16;
typedef short s16x8 __attribute__((ext_vector_type(8)));
typedef u16 u16x4 __attribute__((ext_vector_type(4)));
typedef float f32x4 __attribute__((ext_vector_type(4)));

#define B_ 32
#define L_ 256
#define D_ 1024
#define H_ 8
#define DQ_ 128
#define DS_ 64
#define DM_ 256
#define DF_ 4096

__device__ __forceinline__ u16 f2bf(float f) {
  unsigned u = __float_as_uint(f);
  unsigned r = (u + 0x7FFFu + ((u >> 16) & 1u)) >> 16;
  return (u16)r;
}
__device__ __forceinline__ float bf2f(u16 x) {
  return __uint_as_float(((unsigned)x) << 16);
}

__device__ __forceinline__ f32x4 mfma16(s16x8 a, s16x8 b, f32x4 c) {
  return __builtin_amdgcn_mfma_f32_16x16x32_bf16(a, b, c, 0, 0, 0);
}

#define GLDS16(g, l)                                                        \
  __builtin_amdgcn_global_load_lds(                                         \
      (__attribute__((address_space(1))) const void*)(g),                   \
      (__attribute__((address_space(3))) void*)(l), 16, 0, 0)

// ---------------- 32x32 transpose+convert tile helper
__device__ __forceinline__ void tile_tr(const float* __restrict__ ip,
                                        u16* __restrict__ op, int K, int N,
                                        int bx, int by, float (*t)[33], int tid) {
  const int tx = tid & 31, ty = tid >> 5;
  const long n0 = (long)bx * 32, k0 = (long)by * 32;
#pragma unroll
  for (int i = 0; i < 4; ++i)
    t[ty + i * 8][tx] = ip[(k0 + ty + i * 8) * (long)N + n0 + tx];
  __syncthreads();
#pragma unroll
  for (int i = 0; i < 4; ++i)
    op[(n0 + ty + i * 8) * (long)K + k0 + tx] = f2bf(t[tx][ty + i * 8]);
}

// ---------------- prep: phase2-critical blocks FIRST, then big w-transposes
// grid: [0,3072) qkvT | [3072,3328) conv src b0 | [3328,4352) owT |
//       [4352,8448) w1T | [8448,12544) w2T
__global__ __launch_bounds__(256) void prep(
    const float* __restrict__ qw, const float* __restrict__ kw,
    const float* __restrict__ vw, const float* __restrict__ src,
    const float* __restrict__ ow, const float* __restrict__ w1,
    const float* __restrict__ w2, u16* __restrict__ qwT, u16* __restrict__ kwT,
    u16* __restrict__ vwT, u16* __restrict__ src0b, u16* __restrict__ owT,
    u16* __restrict__ w1T, u16* __restrict__ w2T) {
  const int b = blockIdx.x;
  const int tid = threadIdx.x;
  __shared__ float t[32][33];
  if (b < 3072) {
    const int z = b >> 7, rem = b & 127;
    const int sel = z >> 3, h = z & 7;
    const float* ip = (sel == 0 ? qw : (sel == 1 ? kw : vw)) + (long)h * D_ * DQ_;
    u16* op = (sel == 0 ? qwT : (sel == 1 ? kwT : vwT)) + (long)h * DQ_ * D_;
    tile_tr(ip, op, D_, DQ_, rem & 3, rem >> 2, t, tid);
  } else if (b < 3328) {
    const int rem = b - 3072;
    const int i = (rem * 256 + tid) * 4;
    float4 v = *(const float4*)(src + i);
    u16x4 o = {f2bf(v.x), f2bf(v.y), f2bf(v.z), f2bf(v.w)};
    *(u16x4*)(src0b + i) = o;
  } else if (b < 4352) {
    const int rem = b - 3328;
    tile_tr(ow, owT, D_, D_, rem & 31, rem >> 5, t, tid);
  } else if (b < 8448) {
    const int rem = b - 4352;
    tile_tr(w1, w1T, D_, DF_, rem & 127, rem >> 7, t, tid);
  } else {
    const int rem = b - 8448;
    tile_tr(w2, w2T, DF_, D_, rem & 31, rem >> 5, t, tid);
  }
}

// ---------------- phase2: gemv w/ self-computed hid [0,512) | qkv proj [512,560)
__global__ __launch_bounds__(256) void phase2(
    const float* __restrict__ sf, const float* __restrict__ b1w,
    const float* __restrict__ b1b, const float* __restrict__ b2w,
    const float* __restrict__ b2b, float* __restrict__ biasb,
    const u16* __restrict__ src0b, const u16* __restrict__ qwT,
    const u16* __restrict__ kwT, const u16* __restrict__ vwT,
    const float* __restrict__ qb, const float* __restrict__ kb,
    const float* __restrict__ vb, u16* __restrict__ q0, u16* __restrict__ k0,
    u16* __restrict__ v0T) {
  const int b = blockIdx.x;
  const int tid = threadIdx.x;
  __shared__ float s_sf[DS_];
  __shared__ int wcnt[4];
  __shared__ float sv[DM_];
  __shared__ int si[DM_];
  __shared__ int snnz;
  __shared__ u16 smA[128 * 32];
  __shared__ u16 smB[128 * 32];
  if (b < 512) {
    // bias GEMV; hid computed locally (depends only on raw inputs)
    const int h = b >> 6;
    const int n0 = (b & 63) << 10;
    if (tid < DS_) s_sf[tid] = sf[tid];
    __syncthreads();
    float a = b1b[h * DM_ + tid];
    const float* wp = b1w + (long)h * DS_ * DM_ + tid;
#pragma unroll 8
    for (int s = 0; s < DS_; ++s) a += s_sf[s] * wp[s * DM_];
    a = fmaxf(a, 0.f);
    const unsigned long long bal = __ballot(a > 0.f);
    const int lane = tid & 63, wv = tid >> 6;
    const int pc = __popcll(bal);
    if (lane == 0) wcnt[wv] = pc;
    __syncthreads();
    int base = 0;
    for (int i = 0; i < wv; ++i) base += wcnt[i];
    const int pos = base + __popcll(bal & ((1ull << lane) - 1ull));
    if (a > 0.f) { sv[pos] = a; si[pos] = tid; }
    if (tid == 255) snnz = base + pc;
    __syncthreads();
    const int nnz = snnz;
    const float* wb = b2w + (long)h * DM_ * 65536 + n0 + tid * 4;
    float4 acc = {0.f, 0.f, 0.f, 0.f};
    int j = 0;
    for (; j + 4 <= nnz; j += 4) {
      const float4 a0 = *(const float4*)(wb + (long)si[j] * 65536);
      const float4 a1 = *(const float4*)(wb + (long)si[j + 1] * 65536);
      const float4 a2 = *(const float4*)(wb + (long)si[j + 2] * 65536);
      const float4 a3 = *(const float4*)(wb + (long)si[j + 3] * 65536);
      const float v0 = sv[j], v1 = sv[j + 1], v2 = sv[j + 2], v3 = sv[j + 3];
      acc.x += v0 * a0.x + v1 * a1.x + v2 * a2.x + v3 * a3.x;
      acc.y += v0 * a0.y + v1 * a1.y + v2 * a2.y + v3 * a3.y;
      acc.z += v0 * a0.z + v1 * a1.z + v2 * a2.z + v3 * a3.z;
      acc.w += v0 * a0.w + v1 * a1.w + v2 * a2.w + v3 * a3.w;
    }
    for (; j < nnz; ++j) {
      const float4 a0 = *(const float4*)(wb + (long)si[j] * 65536);
      const float v0 = sv[j];
      acc.x += v0 * a0.x; acc.y += v0 * a0.y; acc.z += v0 * a0.z; acc.w += v0 * a0.w;
    }
    const float4 bb = *(const float4*)(b2b + (long)h * 65536 + n0 + tid * 4);
    float4 o = {acc.x + bb.x, acc.y + bb.y, acc.z + bb.z, acc.w + bb.w};
    *(float4*)(biasb + (long)h * 65536 + n0 + tid * 4) = o;
  } else {
    const int r = b - 512;
    const int z = r >> 1, sel = z >> 3, h = z & 7;
    const long tm = (long)(r & 1) * 128;
    const int K = D_;
    const u16* BT = (sel == 0 ? qwT : (sel == 1 ? kwT : vwT)) + (long)h * DQ_ * D_;
    const float* bias = (sel == 0 ? qb : (sel == 1 ? kb : vb)) + h * DQ_;
    const int lane = tid & 63;
    const int wv = tid >> 6;
    const int wr = wv >> 1, wc = wv & 1;
    const u16* ga = src0b + (tm + (tid >> 2)) * (long)K + (tid & 3) * 8;
    const u16* gb = BT + (long)(tid >> 2) * K + (tid & 3) * 8;
    const long rstep = 64L * K;
    u16* la = &smA[tid * 8];
    u16* lb = &smB[tid * 8];
    f32x4 acc[4][4];
#pragma unroll
    for (int m = 0; m < 4; ++m)
#pragma unroll
      for (int n = 0; n < 4; ++n) acc[m][n] = (f32x4){0.f, 0.f, 0.f, 0.f};
    for (int k0_ = 0; k0_ < K; k0_ += 32) {
      GLDS16(ga + k0_, la);
      GLDS16(ga + rstep + k0_, la + 64 * 32);
      GLDS16(gb + k0_, lb);
      GLDS16(gb + rstep + k0_, lb + 64 * 32);
      __syncthreads();
      s16x8 af[4], bf[4];
      const int ka = (lane >> 4) * 8;
      const int ra = wr * 64 + (lane & 15);
      const int rb = wc * 64 + (lane & 15);
#pragma unroll
      for (int m = 0; m < 4; ++m) af[m] = *(const s16x8*)&smA[(ra + m * 16) * 32 + ka];
#pragma unroll
      for (int n = 0; n < 4; ++n) bf[n] = *(const s16x8*)&smB[(rb + n * 16) * 32 + ka];
#pragma unroll
      for (int m = 0; m < 4; ++m)
#pragma unroll
        for (int n = 0; n < 4; ++n) acc[m][n] = mfma16(af[m], bf[n], acc[m][n]);
      __syncthreads();
    }
    const long crow0 = tm + wr * 64 + ((lane >> 4) * 4);
    const long ccol0 = wc * 64 + (lane & 15);
#pragma unroll
    for (int m = 0; m < 4; ++m)
#pragma unroll
      for (int n = 0; n < 4; ++n)
#pragma unroll
        for (int i = 0; i < 4; ++i) {
          const long row = crow0 + m * 16 + i;
          const long col = ccol0 + n * 16;
          const float v = acc[m][n][i] + bias[col];
          if (sel < 2) {
            u16* o = (sel == 0 ? q0 : k0) + (long)h * L_ * DQ_;
            o[row * DQ_ + col] = f2bf(v);
          } else {
            v0T[(long)h * DQ_ * L_ + col * L_ + row] = f2bf(v);
          }
        }
  }
}

// ---------------- attention (b=0): one wave per (head, 16-row tile), bias fused
__global__ __launch_bounds__(64) void attn_kernel(
    const u16* __restrict__ q0, const u16* __restrict__ k0,
    const u16* __restrict__ v0T, const float* __restrict__ biasb,
    const int* __restrict__ mask, u16* __restrict__ hidden) {
  __shared__ char pbuf[8192];  // [16 rows][256 cols] bf16, XOR-swizzled
  const int lane = threadIdx.x;
  const int h = blockIdx.y;
  const int r0 = blockIdx.x * 16;
  const int lg = lane >> 4;
  const int ll = lane & 15;
  const u16* q = q0 + (long)h * L_ * DQ_;
  const u16* k = k0 + (long)h * L_ * DQ_;
  const u16* v = v0T + (long)h * DQ_ * L_;

  s16x8 aq[4];
#pragma unroll
  for (int kk = 0; kk < 4; ++kk)
    aq[kk] = *(const s16x8*)(q + (long)(r0 + ll) * DQ_ + kk * 32 + lg * 8);
  float sc[16][4];
  const float scale = 0.08838834764831845f;  // 1/sqrt(128)
#pragma unroll
  for (int t = 0; t < 16; ++t) {
    f32x4 a = {0.f, 0.f, 0.f, 0.f};
#pragma unroll
    for (int kk = 0; kk < 4; ++kk) {
      s16x8 bf = *(const s16x8*)(k + (long)(t * 16 + ll) * DQ_ + kk * 32 + lg * 8);
      a = mfma16(aq[kk], bf, a);
    }
#pragma unroll
    for (int i = 0; i < 4; ++i) {
      const int row = r0 + lg * 4 + i;
      const int col = t * 16 + ll;
      float s = a[i] * scale;
      if (mask[row * L_ + col] != 0) s = 1e-9f;
      sc[t][i] = s;
    }
  }
#pragma unroll
  for (int i = 0; i < 4; ++i) {
    float mx = sc[0][i];
#pragma unroll
    for (int t = 1; t < 16; ++t) mx = fmaxf(mx, sc[t][i]);
#pragma unroll
    for (int d = 1; d < 16; d <<= 1) mx = fmaxf(mx, __shfl_xor(mx, d));
    float sum = 0.f;
#pragma unroll
    for (int t = 0; t < 16; ++t) {
      const float e = __expf(sc[t][i] - mx);
      sc[t][i] = e;
      sum += e;
    }
#pragma unroll
    for (int d = 1; d < 16; d <<= 1) sum += __shfl_xor(sum, d);
    const float inv = 1.f / sum;
    const int row = r0 + lg * 4 + i;
#pragma unroll
    for (int t = 0; t < 16; ++t)
      sc[t][i] = sc[t][i] * inv + biasb[(long)h * 65536 + (long)row * 256 + t * 16 + ll];
  }
  // write P (bf16) swizzled; PV (within-wave LDS dep -> compiler waits lgkmcnt)
#pragma unroll
  for (int t = 0; t < 16; ++t)
#pragma unroll
    for (int i = 0; i < 4; ++i) {
      const int lr = lg * 4 + i;
      const int cb = (t * 16 + ll) * 2;
      *(u16*)(pbuf + lr * 512 + (cb ^ ((lr & 7) << 4))) = f2bf(sc[t][i]);
    }
  s16x8 paf[8];
#pragma unroll
  for (int kk = 0; kk < 8; ++kk)
    paf[kk] = *(const s16x8*)(pbuf + ll * 512 + ((kk * 64 + lg * 16) ^ ((ll & 7) << 4)));
#pragma unroll
  for (int n = 0; n < 8; ++n) {
    f32x4 a = {0.f, 0.f, 0.f, 0.f};
#pragma unroll
    for (int kk = 0; kk < 8; ++kk) {
      s16x8 bf = *(const s16x8*)(v + (long)(n * 16 + ll) * 256 + kk * 32 + lg * 8);
      a = mfma16(paf[kk], bf, a);
    }
#pragma unroll
    for (int i = 0; i < 4; ++i) {
      const int row = r0 + lg * 4 + i;
      const int col = n * 16 + ll;
      hidden[(long)row * 1024 + h * 128 + col] = f2bf(a[i]);
    }
  }
}

// ---------------- shared 128x128xK m97 GEMM core (A,BT pre-offset to tile)
__device__ __forceinline__ void g128_core(const u16* __restrict__ A,
                                          const u16* __restrict__ BT, int K,
                                          u16* smA, u16* smB,
                                          f32x4 (&acc)[4][4]) {
  const int tid = threadIdx.x;
  const int lane = tid & 63;
  const int wv = tid >> 6;
  const int wr = wv >> 1, wc = wv & 1;
  const u16* ga = A + (long)(tid >> 2) * K + (tid & 3) * 8;
  const u16* gb = BT + (long)(tid >> 2) * K + (tid & 3) * 8;
  const long rstep = 64L * K;
  u16* la = &smA[tid * 8];
  u16* lb = &smB[tid * 8];
#pragma unroll
  for (int m = 0; m < 4; ++m)
#pragma unroll
    for (int n = 0; n < 4; ++n) acc[m][n] = (f32x4){0.f, 0.f, 0.f, 0.f};
  for (int k0 = 0; k0 < K; k0 += 32) {
    GLDS16(ga + k0, la);
    GLDS16(ga + rstep + k0, la + 64 * 32);
    GLDS16(gb + k0, lb);
    GLDS16(gb + rstep + k0, lb + 64 * 32);
    __syncthreads();
    s16x8 af[4], bf[4];
    const int ka = (lane >> 4) * 8;
    const int ra = wr * 64 + (lane & 15);
    const int rb = wc * 64 + (lane & 15);
#pragma unroll
    for (int m = 0; m < 4; ++m) af[m] = *(const s16x8*)&smA[(ra + m * 16) * 32 + ka];
#pragma unroll
    for (int n = 0; n < 4; ++n) bf[n] = *(const s16x8*)&smB[(rb + n * 16) * 32 + ka];
#pragma unroll
    for (int m = 0; m < 4; ++m)
#pragma unroll
      for (int n = 0; n < 4; ++n) acc[m][n] = mfma16(af[m], bf[n], acc[m][n]);
    __syncthreads();
  }
}

// ---------------- m97-style 128x128 GEMM, f32 out +bias (attn out proj)
__global__ __launch_bounds__(256) void gemm_bt(
    const u16* __restrict__ A, const u16* __restrict__ BT, float* __restrict__ C,
    const float* __restrict__ bias, int K, int ldc) {
  __shared__ u16 smA[128 * 32];
  __shared__ u16 smB[128 * 32];
  const int tid = threadIdx.x;
  const long tm = (long)blockIdx.x * 128;
  const long tn = (long)blockIdx.y * 128;
  f32x4 acc[4][4];
  g128_core(A + tm * K, BT + tn * K, K, smA, smB, acc);
  const int lane = tid & 63;
  const int wv = tid >> 6;
  const int wr = wv >> 1, wc = wv & 1;
  const long crow0 = tm + wr * 64 + ((lane >> 4) * 4);
  const long ccol0 = tn + wc * 64 + (lane & 15);
#pragma unroll
  for (int m = 0; m < 4; ++m)
#pragma unroll
    for (int n = 0; n < 4; ++n)
#pragma unroll
      for (int i = 0; i < 4; ++i) {
        const long row = crow0 + m * 16 + i;
        const long col = ccol0 + n * 16;
        C[row * (long)ldc + col] = acc[m][n][i] + bias[col];
      }
}

// ---------------- 8-phase 256xBN deep-pipelined GEMM (T1+T2+T4+T5)
// EPI: 1 = bf16 out relu(+bias); 2 = bf16 out +bias +bf16 residual
template <int BN, int EPI>
__global__ __launch_bounds__(512, 2) void gemm8p(
    const u16* __restrict__ A, const u16* __restrict__ BT, void* __restrict__ Cv,
    const float* __restrict__ bias, const void* __restrict__ R, int M, int N,
    int K, int ldc) {
  extern __shared__ char lds[];
  constexpr int NR = BN / 64;
  constexpr int NHB = BN / 128;
  constexpr int BUF = 32768 + BN * 128;
  constexpr int WST = (NHB == 2) ? 4 : 2;
  const int tid = threadIdx.x;
  const int lane = tid & 63;
  const int w = tid >> 6;
  const int wr = w >> 2, wc = w & 3;

  const int total = gridDim.x;
  int bid = blockIdx.x;
  int s = ((total & 7) == 0) ? ((bid & 7) * (total >> 3) + (bid >> 3)) : bid;
  const int gn = N / BN;
  const long tm = (long)(s / gn) * 256;
  const long tn = (long)(s % gn) * BN;
  const int NT = K >> 6;

  auto stageA = [&](int half, int t) {
    char* hb = lds + (long)(t & 1) * BUF + half * 16384;
    const u16* g = A + (tm + half * 128) * (long)K + (long)t * 64;
#pragma unroll
    for (int j = 0; j < 2; ++j) {
      const int idx = j * 512 + tid;
      const int r = idx >> 3;
      const int c16 = (idx & 7) ^ (r & 7);
      GLDS16(g + (long)r * K + c16 * 8, hb + idx * 16);
    }
  };
  auto stageB = [&](int half, int t) {
    char* hb = lds + (long)(t & 1) * BUF + 32768 + half * 16384;
    const u16* g = BT + (tn + half * 128) * (long)K + (long)t * 64;
#pragma unroll
    for (int j = 0; j < 2; ++j) {
      const int idx = j * 512 + tid;
      const int r = idx >> 3;
      const int c16 = (idx & 7) ^ (r & 7);
      GLDS16(g + (long)r * K + c16 * 8, hb + idx * 16);
    }
  };

  stageA(0, 0);
  stageA(1, 0);
  stageB(0, 0);
  if (NHB == 2) stageB(1, 0);
  stageB(0, 1);
  if (NHB == 2) stageB(1, 1);
  asm volatile("s_waitcnt vmcnt(%0)" ::"n"(WST) : "memory");
  __builtin_amdgcn_s_barrier();

  f32x4 acc[8][NR];
#pragma unroll
  for (int m = 0; m < 8; ++m)
#pragma unroll
    for (int n = 0; n < NR; ++n) acc[m][n] = (f32x4){0.f, 0.f, 0.f, 0.f};

  const int lk = (lane >> 4) * 16;
  const int lr = lane & 15;

  for (int t = 0; t < NT; ++t) {
    const char* bp = lds + (long)(t & 1) * BUF;
    s16x8 bfr[NR][2];
#pragma unroll
    for (int p = 0; p < 4; ++p) {
      if (p == 0) {
#pragma unroll
        for (int ni = 0; ni < NR; ++ni) {
          const int brow = wc * (BN / 4) + ni * 16 + lr;
#pragma unroll
          for (int ks = 0; ks < 2; ++ks) {
            const int kb = (ks * 64 + lk) ^ ((brow & 7) << 4);
            bfr[ni][ks] = *(const s16x8*)(bp + 32768 + brow * 128 + kb);
          }
        }
      }
      s16x8 afr[2][2];
#pragma unroll
      for (int rI = 0; rI < 2; ++rI) {
        const int arow = wr * 128 + (2 * p + rI) * 16 + lr;
#pragma unroll
        for (int ks = 0; ks < 2; ++ks) {
          const int kb = (ks * 64 + lk) ^ ((arow & 7) << 4);
          afr[rI][ks] = *(const s16x8*)(bp + arow * 128 + kb);
        }
      }
      if (p == 0) { if (t + 1 < NT) stageA(0, t + 1); }
      else if (p == 1) { if (t + 1 < NT) stageA(1, t + 1); }
      else if (p == 2) { if (t + 2 < NT) stageB(0, t + 2); }
      else { if (NHB == 2 && t + 2 < NT) stageB(1, t + 2); }
      __builtin_amdgcn_s_barrier();
      __builtin_amdgcn_s_setprio(1);
#pragma unroll
      for (int rI = 0; rI < 2; ++rI)
#pragma unroll
        for (int ni = 0; ni < NR; ++ni)
#pragma unroll
          for (int ks = 0; ks < 2; ++ks)
            acc[2 * p + rI][ni] = mfma16(afr[rI][ks], bfr[ni][ks], acc[2 * p + rI][ni]);
      __builtin_amdgcn_s_setprio(0);
      if (p == 3) {
        if (t + 2 < NT) {
          asm volatile("s_waitcnt vmcnt(%0)" ::"n"(WST) : "memory");
        } else if (t + 1 < NT) {
          asm volatile("s_waitcnt vmcnt(0)" ::: "memory");
        }
      }
      __builtin_amdgcn_s_barrier();
    }
  }

  const long crow0 = tm + wr * 128 + ((lane >> 4) * 4);
  const long ccol0 = tn + wc * (BN / 4) + lr;
#pragma unroll
  for (int m = 0; m < 8; ++m) {
#pragma unroll
    for (int n = 0; n < NR; ++n) {
#pragma unroll
      for (int i = 0; i < 4; ++i) {
        const long row = crow0 + m * 16 + i;
        const long col = ccol0 + n * 16;
        const float v = acc[m][n][i] + bias[col];
        if constexpr (EPI == 1) {
          ((u16*)Cv)[row * (long)ldc + col] = f2bf(fmaxf(v, 0.f));
        } else {
          const float r = bf2f(((const u16*)R)[row * (long)ldc + col]);
          ((u16*)Cv)[row * (long)ldc + col] = f2bf(v + r);
        }
      }
    }
  }
}

// ---------------- layernorm over D=1024
// MODE 0: in f32 + add f32 (attn row, row%L), out bf16
// MODE 1: in bf16, out f32
template <int MODE>
__global__ __launch_bounds__(256) void ln_kernel(
    const void* __restrict__ in0v, const float* __restrict__ add1,
    const float* __restrict__ g, const float* __restrict__ bb,
    void* __restrict__ outv) {
  const int tid = threadIdx.x;
  const long row = blockIdx.x;
  float4 v;
  if constexpr (MODE == 0) {
    v = ((const float4*)((const float*)in0v + row * D_))[tid];
    const float4 u = ((const float4*)(add1 + (row & (L_ - 1)) * D_))[tid];
    v.x += u.x; v.y += u.y; v.z += u.z; v.w += u.w;
  } else {
    const uint2 pk = *(const uint2*)((const u16*)in0v + row * D_ + tid * 4);
    v.x = __uint_as_float((pk.x & 0xFFFFu) << 16);
    v.y = __uint_as_float(pk.x & 0xFFFF0000u);
    v.z = __uint_as_float((pk.y & 0xFFFFu) << 16);
    v.w = __uint_as_float(pk.y & 0xFFFF0000u);
  }
  float s = v.x + v.y + v.z + v.w;
  float q = v.x * v.x + v.y * v.y + v.z * v.z + v.w * v.w;
#pragma unroll
  for (int d = 1; d < 64; d <<= 1) { s += __shfl_xor(s, d); q += __shfl_xor(q, d); }
  __shared__ float ss[4], sq[4];
  const int wv = tid >> 6;
  if ((tid & 63) == 0) { ss[wv] = s; sq[wv] = q; }
  __syncthreads();
  s = ss[0] + ss[1] + ss[2] + ss[3];
  q = sq[0] + sq[1] + sq[2] + sq[3];
  const float mu = s * (1.f / D_);
  const float var = q * (1.f / D_) - mu * mu;
  const float rs = rsqrtf(var + 1e-5f);
  const float4 gv = ((const float4*)g)[tid];
  const float4 bv = ((const float4*)bb)[tid];
  float4 o;
  o.x = (v.x - mu) * rs * gv.x + bv.x;
  o.y = (v.y - mu) * rs * gv.y + bv.y;
  o.z = (v.z - mu) * rs * gv.z + bv.z;
  o.w = (v.w - mu) * rs * gv.w + bv.w;
  if constexpr (MODE == 0) {
    uint2 pk;
    pk.x = (unsigned)f2bf(o.x) | ((unsigned)f2bf(o.y) << 16);
    pk.y = (unsigned)f2bf(o.z) | ((unsigned)f2bf(o.w) << 16);
    *(uint2*)((u16*)outv + row * D_ + tid * 4) = pk;
  } else {
    ((float4*)((float*)outv + row * D_))[tid] = o;
  }
}

extern "C" void kernel_launch(void* const* d_in, const int* in_sizes, int n_in,
                              void* d_out, int out_size, void* d_ws, size_t ws_size,
                              hipStream_t stream) {
  (void)in_sizes; (void)n_in; (void)out_size; (void)ws_size;
  const float* src = (const float*)d_in[0];
  const float* sf = (const float*)d_in[1];
  const int* mask = (const int*)d_in[2];
  const float* qw = (const float*)d_in[3];
  const float* qb = (const float*)d_in[4];
  const float* kw = (const float*)d_in[5];
  const float* kb = (const float*)d_in[6];
  const float* vw = (const float*)d_in[7];
  const float* vb = (const float*)d_in[8];
  const float* b1w = (const float*)d_in[9];
  const float* b1b = (const float*)d_in[10];
  const float* b2w = (const float*)d_in[11];
  const float* b2b = (const float*)d_in[12];
  const float* ow = (const float*)d_in[13];
  const float* ob = (const float*)d_in[14];
  const float* ln1g = (const float*)d_in[15];
  const float* ln1b = (const float*)d_in[16];
  const float* ln2g = (const float*)d_in[17];
  const float* ln2b = (const float*)d_in[18];
  const float* w1 = (const float*)d_in[19];
  const float* bf1 = (const float*)d_in[20];
  const float* w2 = (const float*)d_in[21];
  const float* bf2 = (const float*)d_in[22];
  float* out = (float*)d_out;

  char* ws = (char*)d_ws;
  size_t off = 0;
  auto alloc = [&](size_t bytes) {
    void* p = ws + off;
    off += (bytes + 255) & ~(size_t)255;
    return p;
  };
  u16* qwT = (u16*)alloc((size_t)H_ * DQ_ * D_ * 2);
  u16* kwT = (u16*)alloc((size_t)H_ * DQ_ * D_ * 2);
  u16* vwT = (u16*)alloc((size_t)H_ * DQ_ * D_ * 2);
  u16* owT = (u16*)alloc((size_t)D_ * D_ * 2);
  u16* w1T = (u16*)alloc((size_t)DF_ * D_ * 2);
  u16* w2T = (u16*)alloc((size_t)D_ * DF_ * 2);
  u16* src0b = (u16*)alloc((size_t)L_ * D_ * 2);
  u16* q0 = (u16*)alloc((size_t)H_ * L_ * DQ_ * 2);
  u16* k0 = (u16*)alloc((size_t)H_ * L_ * DQ_ * 2);
  u16* v0T = (u16*)alloc((size_t)H_ * DQ_ * L_ * 2);
  float* biasb = (float*)alloc((size_t)H_ * L_ * L_ * 4);
  u16* hidden = (u16*)alloc((size_t)L_ * D_ * 2);
  float* attnvec = (float*)alloc((size_t)L_ * D_ * 4);
  u16* xb = (u16*)alloc((size_t)B_ * L_ * D_ * 2);
  u16* ffnh = (u16*)alloc((size_t)B_ * L_ * DF_ * 2);
  u16* yb = (u16*)alloc((size_t)B_ * L_ * D_ * 2);

  hipFuncSetAttribute((const void*)gemm8p<256, 1>,
                      hipFuncAttributeMaxDynamicSharedMemorySize, 131072);
  hipFuncSetAttribute((const void*)gemm8p<128, 2>,
                      hipFuncAttributeMaxDynamicSharedMemorySize, 98304);

  const dim3 b256(256);
  // K1: qkvT + src conv first, then ow/w1/w2 transposes
  prep<<<dim3(12544), b256, 0, stream>>>(qw, kw, vw, src, ow, w1, w2, qwT, kwT,
                                         vwT, src0b, owT, w1T, w2T);
  // K2: bias GEMV (self-computed hid) || QKV projections
  phase2<<<dim3(560), b256, 0, stream>>>(sf, b1w, b1b, b2w, b2b, biasb, src0b,
                                         qwT, kwT, vwT, qb, kb, vb, q0, k0, v0T);
  // K3: attention (b=0), bias fused post-softmax -> hidden
  attn_kernel<<<dim3(16, H_), dim3(64), 0, stream>>>(q0, k0, v0T, biasb, mask,
                                                     hidden);
  // K4: attn out projection -> attnvec f32
  gemm_bt<<<dim3(2, 8), b256, 0, stream>>>(hidden, owT, attnvec, ob, D_, D_);
  // K5: LN1 -> xb bf16
  ln_kernel<0><<<dim3(B_ * L_), b256, 0, stream>>>(src, attnvec, ln1g, ln1b, xb);
  // K6: FFN1 relu(x @ w1 + bf1) -> ffnh bf16
  gemm8p<256, 1><<<dim3(512), dim3(512), 131072, stream>>>(
      xb, w1T, ffnh, bf1, nullptr, B_ * L_, DF_, D_, DF_);
  // K7: FFN2 yb = bf16(ffnh @ w2 + bf2 + xb)
  gemm8p<128, 2><<<dim3(256), dim3(512), 98304, stream>>>(
      ffnh, w2T, yb, bf2, xb, B_ * L_, D_, DF_, D_);
  // K8: LN2 -> d_out (f32)
  ln_kernel<1><<<dim3(B_ * L_), b256, 0, stream>>>(yb, nullptr, ln2g, ln2b, out);
}